// Round 2
// baseline (38894.214 us; speedup 1.0000x reference)
//
#include <hip/hip_runtime.h>
#include <hip/hip_bf16.h>

// IN=128, H=512, N=2048, W=64, OUT=128, R=4, T=128, B=64
// ctrl_in=384, gate K=896, gate rows=2048, out+key rows=448
#define EPSF 1e-8f

typedef __attribute__((ext_vector_type(8))) __bf16 bf8;
typedef __attribute__((ext_vector_type(4))) float f4;

__device__ __forceinline__ short f2bf(float f) {
  union { __hip_bfloat16 b; short s; } u;
  u.b = __float2bfloat16(f);
  return u.s;
}
__device__ __forceinline__ float sigf(float x) { return 1.f / (1.f + __expf(-x)); }
__device__ __forceinline__ float red16(float v) {
  v += __shfl_xor(v, 1); v += __shfl_xor(v, 2);
  v += __shfl_xor(v, 4); v += __shfl_xor(v, 8);
  return v;
}

// Two-level grid barrier: 8 group counters (32 blocks each) -> root -> generation.
// bar[g*16] g<8: group counters; bar[128]: root; bar[160]: generation.
// Requires all 256 blocks co-resident (grid == CU count, 1 block/CU).
__device__ void gsync(unsigned* bar) {
  __syncthreads();
  if (threadIdx.x == 0) {
    unsigned gen = __hip_atomic_load(&bar[160], __ATOMIC_RELAXED, __HIP_MEMORY_SCOPE_AGENT);
    __threadfence();  // release: make this block's writes visible device-wide
    unsigned g = blockIdx.x >> 5;
    bool last = false;
    if (atomicAdd(&bar[g * 16], 1u) == 31u)
      if (atomicAdd(&bar[128], 1u) == 7u) last = true;
    if (last) {
      for (int k = 0; k < 8; ++k)
        __hip_atomic_store(&bar[k * 16], 0u, __ATOMIC_RELAXED, __HIP_MEMORY_SCOPE_AGENT);
      __hip_atomic_store(&bar[128], 0u, __ATOMIC_RELAXED, __HIP_MEMORY_SCOPE_AGENT);
      __hip_atomic_store(&bar[160], gen + 1u, __ATOMIC_RELEASE, __HIP_MEMORY_SCOPE_AGENT);
    } else {
      while (__hip_atomic_load(&bar[160], __ATOMIC_ACQUIRE, __HIP_MEMORY_SCOPE_AGENT) == gen)
        __builtin_amdgcn_s_sleep(1);
    }
    __threadfence();  // acquire side
  }
  __syncthreads();
}

__global__ __launch_bounds__(512) void mann_mega(
    const float* __restrict__ x_seq, const float* __restrict__ Wih,
    const float* __restrict__ Whh, const float* __restrict__ bih,
    const float* __restrict__ bhh, const float* __restrict__ Wout,
    const float* __restrict__ boutp, const float* __restrict__ Wkey,
    const float* __restrict__ bkeyp, const float* __restrict__ alphap,
    const float* __restrict__ gammap, float* __restrict__ out, char* ws) {
  // workspace layout
  float* M = (float*)(ws);                    // 33554432
  float* rwA = (float*)(ws + 33554432);       // 2097152
  float* rwB = (float*)(ws + 35651584);       // 2097152
  float* usage = (float*)(ws + 37748736);     // 524288
  float* cst = (float*)(ws + 38273024);       // 131072
  short* hA = (short*)(ws + 38404096);        // 65536
  short* hB = (short*)(ws + 38469632);        // 65536
  float* rvp = (float*)(ws + 38535168);       // 262144  read_vec partials [b][ch][256]
  float* keys = (float*)(ws + 38797312);      // 81920
  float* sA = (float*)(ws + 38879232);        // 4096    sum partials [b][r][ch]
  float* sB = (float*)(ws + 38883328);        // 4096
  int* lu_idx = (int*)(ws + 38887424);        // 1024
  unsigned* bar = (unsigned*)(ws + 38888448); // 1024 (memset 0 by host each call)
  short* Wc = (short*)(ws + 38889472);        // 3670016
  short* Wkb = (short*)(ws + 42559488);       // 458752 -> end 43018240

  __shared__ union {
    struct { short Xs[64 * 72]; short Ws[32 * 72]; float gbuf[64 * 33]; } g;
    struct { float sv[512]; int si[512]; float wsum[32]; } r;
    struct { float rvacc[256]; } u;
  } sm;

  const int tid = threadIdx.x;
  const int lane = tid & 63;
  const int wv = tid >> 6;

  // ---------------- prologue: weight cvt + state init ----------------
  {
    const unsigned gid = blockIdx.x * 512 + tid;
    const unsigned gs = 256 * 512;
    for (unsigned i = gid; i < 2048u * 896u; i += gs) {
      unsigned row = i / 896u, k = i - row * 896u;
      float v = (k < 384u) ? Wih[row * 384u + k] : Whh[row * 512u + (k - 384u)];
      Wc[i] = f2bf(v);
    }
    for (unsigned i = gid; i < 448u * 512u; i += gs) {
      unsigned row = i >> 9, k = i & 511u;
      float v = (row < 128u) ? Wout[row * 512u + k] : Wkey[(row - 128u) * 512u + k];
      Wkb[i] = f2bf(v);
    }
    for (unsigned i = gid; i < 8388608u; i += gs) M[i] = 1e-6f;
    for (unsigned i = gid; i < 524288u; i += gs) rwA[i] = 0.f;
    for (unsigned i = gid; i < 131072u; i += gs) usage[i] = 0.f;
    if (gid < 32768u) { cst[gid] = 0.f; hA[gid] = 0; }
    for (unsigned i = gid; i < 65536u; i += gs) rvp[i] = 0.f;
    if (gid < 1024u) sA[gid] = 0.25f;  // prev denom partials -> sum 1 (w_prev=0 via rwA=0)
  }
  gsync(bar);

  for (int t = 0; t < 128; ++t) {
    const short* hP = (t & 1) ? hB : hA;
    short* hN = (t & 1) ? hA : hB;
    const float* rwP = (t & 1) ? rwB : rwA;
    float* rwN = (t & 1) ? rwA : rwB;
    const float* sP = (t & 1) ? sB : sA;
    float* sN = (t & 1) ? sA : sB;

    // ---------------- P1: gates GEMM + LSTM cell (blocks 0..63) ----------------
    if (blockIdx.x < 64) {
      const int m = lane & 15, quad = lane >> 4;
      const int j0 = blockIdx.x * 8;
      f4 acc0 = {0.f, 0.f, 0.f, 0.f}, acc1 = {0.f, 0.f, 0.f, 0.f};
      for (int kc = 0; kc < 14; ++kc) {
        const int kbase = kc * 64;
        __syncthreads();
        if (kbase < 128) {
          for (int p = 0; p < 4; ++p) {
            int i = p * 512 + tid, row = i >> 5, kp = i & 31;
            float2 v = *(const float2*)&x_seq[((size_t)t * 64 + row) * 128 + kbase + kp * 2];
            short2 o; o.x = f2bf(v.x); o.y = f2bf(v.y);
            *(short2*)&sm.g.Xs[row * 72 + kp * 2] = o;
          }
        } else if (kbase < 384) {
          for (int p = 0; p < 4; ++p) {
            int i = p * 512 + tid, row = i >> 5, kp = i & 31;
            int col = kbase - 128 + kp * 2;
            float a0 = 0.f, a1 = 0.f;
#pragma unroll
            for (int cc = 0; cc < 4; ++cc) {
              float2 v = *(const float2*)&rvp[(row * 4 + cc) * 256 + col];
              a0 += v.x; a1 += v.y;
            }
            short2 o; o.x = f2bf(a0); o.y = f2bf(a1);
            *(short2*)&sm.g.Xs[row * 72 + kp * 2] = o;
          }
        } else {
          for (int p = 0; p < 4; ++p) {
            int i = p * 512 + tid, row = i >> 5, kp = i & 31;
            *(short2*)&sm.g.Xs[row * 72 + kp * 2] =
                *(const short2*)&hP[row * 512 + (kbase - 384) + kp * 2];
          }
        }
        for (int p = 0; p < 2; ++p) {
          int i = p * 512 + tid, row = i >> 5, kp = i & 31;
          int g = row >> 3, jj = row & 7;
          int grow = g * 512 + j0 + jj;
          *(short2*)&sm.g.Ws[row * 72 + kp * 2] =
              *(const short2*)&Wc[(size_t)grow * 896 + kbase + kp * 2];
        }
        __syncthreads();
        if (wv < 4) {
#pragma unroll
          for (int ki = 0; ki < 2; ++ki) {
            int ko = ki * 32 + quad * 8;
            bf8 a = *(const bf8*)&sm.g.Xs[(16 * wv + m) * 72 + ko];
            bf8 b0 = *(const bf8*)&sm.g.Ws[m * 72 + ko];
            bf8 b1 = *(const bf8*)&sm.g.Ws[(16 + m) * 72 + ko];
            acc0 = __builtin_amdgcn_mfma_f32_16x16x32_bf16(a, b0, acc0, 0, 0, 0);
            acc1 = __builtin_amdgcn_mfma_f32_16x16x32_bf16(a, b1, acc1, 0, 0, 0);
          }
        }
      }
      __syncthreads();
      if (wv < 4) {
#pragma unroll
        for (int reg = 0; reg < 4; ++reg) {
          int b = 16 * wv + quad * 4 + reg;
          sm.g.gbuf[b * 33 + m] = acc0[reg];
          sm.g.gbuf[b * 33 + 16 + m] = acc1[reg];
        }
      }
      __syncthreads();
      {
        int b = tid & 63, jj = tid >> 6, j = j0 + jj;
        float gi = sm.g.gbuf[b * 33 + jj] + bih[j] + bhh[j];
        float gf = sm.g.gbuf[b * 33 + 8 + jj] + bih[512 + j] + bhh[512 + j];
        float gg = sm.g.gbuf[b * 33 + 16 + jj] + bih[1024 + j] + bhh[1024 + j];
        float go = sm.g.gbuf[b * 33 + 24 + jj] + bih[1536 + j] + bhh[1536 + j];
        float co = cst[b * 512 + j];
        float cn = sigf(gf) * co + sigf(gi) * tanhf(gg);
        float hn = sigf(go) * tanhf(cn);
        cst[b * 512 + j] = cn;
        hN[b * 512 + j] = f2bf(hn);
      }
    }
    gsync(bar);

    // ---------------- P2: out + keys GEMM (blocks 0..13) ----------------
    if (blockIdx.x < 14) {
      const int m = lane & 15, quad = lane >> 4;
      const int row0 = blockIdx.x * 32;
      f4 a0 = {0.f, 0.f, 0.f, 0.f}, a1 = {0.f, 0.f, 0.f, 0.f};
      for (int kc = 0; kc < 8; ++kc) {
        int kbase = kc * 64;
        __syncthreads();
        for (int p = 0; p < 4; ++p) {
          int i = p * 512 + tid, row = i >> 5, kp = i & 31;
          *(short2*)&sm.g.Xs[row * 72 + kp * 2] =
              *(const short2*)&hN[row * 512 + kbase + kp * 2];
        }
        for (int p = 0; p < 2; ++p) {
          int i = p * 512 + tid, row = i >> 5, kp = i & 31;
          *(short2*)&sm.g.Ws[row * 72 + kp * 2] =
              *(const short2*)&Wkb[(size_t)(row0 + row) * 512 + kbase + kp * 2];
        }
        __syncthreads();
        if (wv < 4) {
#pragma unroll
          for (int ki = 0; ki < 2; ++ki) {
            int ko = ki * 32 + quad * 8;
            bf8 a = *(const bf8*)&sm.g.Xs[(16 * wv + m) * 72 + ko];
            bf8 b0 = *(const bf8*)&sm.g.Ws[m * 72 + ko];
            bf8 b1 = *(const bf8*)&sm.g.Ws[(16 + m) * 72 + ko];
            a0 = __builtin_amdgcn_mfma_f32_16x16x32_bf16(a, b0, a0, 0, 0, 0);
            a1 = __builtin_amdgcn_mfma_f32_16x16x32_bf16(a, b1, a1, 0, 0, 0);
          }
        }
      }
      if (wv < 4) {
#pragma unroll
        for (int f = 0; f < 2; ++f) {
          f4 av = f ? a1 : a0;
#pragma unroll
          for (int reg = 0; reg < 4; ++reg) {
            int b = 16 * wv + quad * 4 + reg;
            int grow = row0 + f * 16 + m;
            float val = av[reg];
            if (grow < 128)
              out[((size_t)t * 64 + b) * 128 + grow] = val + boutp[grow];
            else
              keys[b * 320 + (grow - 128)] = val + bkeyp[grow - 128];
          }
        }
      }
    }
    gsync(bar);

    // ---------------- P3: cosine sim + exp + partial sums + argmin ----------------
    {
      const int s = lane & 15, q = lane >> 4;
      const int b = blockIdx.x >> 2, ch = blockIdx.x & 3;
      const float4* M4 = (const float4*)M;
      const float4* K4 = (const float4*)keys;
      float4 kn[4];
#pragma unroll
      for (int r4 = 0; r4 < 4; ++r4) {
        float4 k4 = K4[b * 80 + r4 * 16 + s];
        float ss = k4.x * k4.x + k4.y * k4.y + k4.z * k4.z + k4.w * k4.w;
        ss = red16(ss);
        float iv = 1.f / (sqrtf(ss) + EPSF);
        kn[r4].x = k4.x * iv; kn[r4].y = k4.y * iv;
        kn[r4].z = k4.z * iv; kn[r4].w = k4.w * iv;
      }
      float es0 = 0.f, es1 = 0.f, es2 = 0.f, es3 = 0.f;
      for (int i = 0; i < 16; ++i) {
        int n = ch * 512 + wv * 64 + i * 4 + q;
        float4 m4 = M4[((size_t)b * 2048 + n) * 16 + s];
        float ssm = m4.x * m4.x + m4.y * m4.y + m4.z * m4.z + m4.w * m4.w;
        float d0 = m4.x * kn[0].x + m4.y * kn[0].y + m4.z * kn[0].z + m4.w * kn[0].w;
        float d1 = m4.x * kn[1].x + m4.y * kn[1].y + m4.z * kn[1].z + m4.w * kn[1].w;
        float d2 = m4.x * kn[2].x + m4.y * kn[2].y + m4.z * kn[2].z + m4.w * kn[2].w;
        float d3 = m4.x * kn[3].x + m4.y * kn[3].y + m4.z * kn[3].z + m4.w * kn[3].w;
        ssm = red16(ssm);
        d0 = red16(d0); d1 = red16(d1); d2 = red16(d2); d3 = red16(d3);
        float iv = 1.f / (sqrtf(ssm) + EPSF);
        if (s == 0) {
          float e0 = __expf(d0 * iv), e1 = __expf(d1 * iv);
          float e2 = __expf(d2 * iv), e3 = __expf(d3 * iv);
          rwN[(b * 4 + 0) * 2048 + n] = e0;
          rwN[(b * 4 + 1) * 2048 + n] = e1;
          rwN[(b * 4 + 2) * 2048 + n] = e2;
          rwN[(b * 4 + 3) * 2048 + n] = e3;
          es0 += e0; es1 += e1; es2 += e2; es3 += e3;
        }
      }
      es0 += __shfl_xor(es0, 16); es0 += __shfl_xor(es0, 32);
      es1 += __shfl_xor(es1, 16); es1 += __shfl_xor(es1, 32);
      es2 += __shfl_xor(es2, 16); es2 += __shfl_xor(es2, 32);
      es3 += __shfl_xor(es3, 16); es3 += __shfl_xor(es3, 32);
      if (lane == 0) {
        sm.r.wsum[wv * 4 + 0] = es0; sm.r.wsum[wv * 4 + 1] = es1;
        sm.r.wsum[wv * 4 + 2] = es2; sm.r.wsum[wv * 4 + 3] = es3;
      }
      __syncthreads();
      if (tid < 4) {
        float ssum = 0.f;
        for (int w8 = 0; w8 < 8; ++w8) ssum += sm.r.wsum[w8 * 4 + tid];
        sN[(b * 4 + tid) * 4 + ch] = ssum;
      }
      if (ch == 0) {
        float vm = INFINITY;
        int im = 0x7fffffff;
        for (int i2 = 0; i2 < 4; ++i2) {
          int n = i2 * 512 + tid;  // strictly increasing -> strict < keeps first min
          float v = usage[b * 2048 + n];
          if (v < vm) { vm = v; im = n; }
        }
        sm.r.sv[tid] = vm; sm.r.si[tid] = im;
        __syncthreads();
        for (int off = 256; off > 0; off >>= 1) {
          if (tid < off) {
            float v2 = sm.r.sv[tid + off]; int j2 = sm.r.si[tid + off];
            if (v2 < sm.r.sv[tid] || (v2 == sm.r.sv[tid] && j2 < sm.r.si[tid])) {
              sm.r.sv[tid] = v2; sm.r.si[tid] = j2;
            }
          }
          __syncthreads();
        }
        if (tid == 0) lu_idx[b] = sm.r.si[0];
      }
    }
    gsync(bar);

    // ---------------- P4: read_vec + memory write + usage update ----------------
    {
      const int s = lane & 15, q = lane >> 4;
      const int b = blockIdx.x >> 2, ch = blockIdx.x & 3;
      float4* M4 = (float4*)M;
      const float4* K4 = (const float4*)keys;
      const float sa = sigf(alphap[0]);
      const float gam = gammap[0];
      const int lu = lu_idx[b];
      const float4 wk = K4[b * 80 + 64 + s];
      float iN[4], iP[4];
#pragma unroll
      for (int r4 = 0; r4 < 4; ++r4) {
        float t0 = sN[(b * 4 + r4) * 4 + 0] + sN[(b * 4 + r4) * 4 + 1] +
                   sN[(b * 4 + r4) * 4 + 2] + sN[(b * 4 + r4) * 4 + 3];
        iN[r4] = 1.f / t0;
        float t1 = sP[(b * 4 + r4) * 4 + 0] + sP[(b * 4 + r4) * 4 + 1] +
                   sP[(b * 4 + r4) * 4 + 2] + sP[(b * 4 + r4) * 4 + 3];
        iP[r4] = 1.f / t1;
      }
      if (tid < 256) sm.u.rvacc[tid] = 0.f;
      __syncthreads();
      float4 rv0 = {0,0,0,0}, rv1 = {0,0,0,0}, rv2 = {0,0,0,0}, rv3 = {0,0,0,0};
      for (int i = 0; i < 16; ++i) {
        int n = ch * 512 + wv * 64 + i * 4 + q;
        size_t mi = ((size_t)b * 2048 + n) * 16 + s;
        float4 m4 = M4[mi];
        float e0 = rwN[(b * 4 + 0) * 2048 + n] * iN[0];
        float e1 = rwN[(b * 4 + 1) * 2048 + n] * iN[1];
        float e2 = rwN[(b * 4 + 2) * 2048 + n] * iN[2];
        float e3 = rwN[(b * 4 + 3) * 2048 + n] * iN[3];
        rv0.x += e0 * m4.x; rv0.y += e0 * m4.y; rv0.z += e0 * m4.z; rv0.w += e0 * m4.w;
        rv1.x += e1 * m4.x; rv1.y += e1 * m4.y; rv1.z += e1 * m4.z; rv1.w += e1 * m4.w;
        rv2.x += e2 * m4.x; rv2.y += e2 * m4.y; rv2.z += e2 * m4.z; rv2.w += e2 * m4.w;
        rv3.x += e3 * m4.x; rv3.y += e3 * m4.y; rv3.z += e3 * m4.z; rv3.w += e3 * m4.w;
        float wps = rwP[(b * 4 + 0) * 2048 + n] * iP[0] +
                    rwP[(b * 4 + 1) * 2048 + n] * iP[1] +
                    rwP[(b * 4 + 2) * 2048 + n] * iP[2] +
                    rwP[(b * 4 + 3) * 2048 + n] * iP[3];
        float onehot = (n == lu) ? 1.f : 0.f;
        float ww = sa * wps + (1.f - sa) * onehot;
        float keep = 1.f - onehot;
        float4 mn;
        mn.x = m4.x * keep + ww * wk.x;
        mn.y = m4.y * keep + ww * wk.y;
        mn.z = m4.z * keep + ww * wk.z;
        mn.w = m4.w * keep + ww * wk.w;
        M4[mi] = mn;
        if (s == 0)
          usage[b * 2048 + n] = gam * usage[b * 2048 + n] + (e0 + e1 + e2 + e3) + ww;
      }
#define REDQ(v) { v += __shfl_xor(v, 16); v += __shfl_xor(v, 32); }
      REDQ(rv0.x) REDQ(rv0.y) REDQ(rv0.z) REDQ(rv0.w)
      REDQ(rv1.x) REDQ(rv1.y) REDQ(rv1.z) REDQ(rv1.w)
      REDQ(rv2.x) REDQ(rv2.y) REDQ(rv2.z) REDQ(rv2.w)
      REDQ(rv3.x) REDQ(rv3.y) REDQ(rv3.z) REDQ(rv3.w)
#undef REDQ
      if (q == 0) {
        atomicAdd(&sm.u.rvacc[0 * 64 + s * 4 + 0], rv0.x);
        atomicAdd(&sm.u.rvacc[0 * 64 + s * 4 + 1], rv0.y);
        atomicAdd(&sm.u.rvacc[0 * 64 + s * 4 + 2], rv0.z);
        atomicAdd(&sm.u.rvacc[0 * 64 + s * 4 + 3], rv0.w);
        atomicAdd(&sm.u.rvacc[1 * 64 + s * 4 + 0], rv1.x);
        atomicAdd(&sm.u.rvacc[1 * 64 + s * 4 + 1], rv1.y);
        atomicAdd(&sm.u.rvacc[1 * 64 + s * 4 + 2], rv1.z);
        atomicAdd(&sm.u.rvacc[1 * 64 + s * 4 + 3], rv1.w);
        atomicAdd(&sm.u.rvacc[2 * 64 + s * 4 + 0], rv2.x);
        atomicAdd(&sm.u.rvacc[2 * 64 + s * 4 + 1], rv2.y);
        atomicAdd(&sm.u.rvacc[2 * 64 + s * 4 + 2], rv2.z);
        atomicAdd(&sm.u.rvacc[2 * 64 + s * 4 + 3], rv2.w);
        atomicAdd(&sm.u.rvacc[3 * 64 + s * 4 + 0], rv3.x);
        atomicAdd(&sm.u.rvacc[3 * 64 + s * 4 + 1], rv3.y);
        atomicAdd(&sm.u.rvacc[3 * 64 + s * 4 + 2], rv3.z);
        atomicAdd(&sm.u.rvacc[3 * 64 + s * 4 + 3], rv3.w);
      }
      __syncthreads();
      if (tid < 256) rvp[(b * 4 + ch) * 256 + tid] = sm.u.rvacc[tid];
    }
    gsync(bar);
  }
}

extern "C" void kernel_launch(void* const* d_in, const int* in_sizes, int n_in,
                              void* d_out, int out_size, void* d_ws, size_t ws_size,
                              hipStream_t stream) {
  const float* x_seq = (const float*)d_in[0];
  const float* Wih = (const float*)d_in[1];
  const float* Whh = (const float*)d_in[2];
  const float* bih = (const float*)d_in[3];
  const float* bhh = (const float*)d_in[4];
  const float* Wout = (const float*)d_in[5];
  const float* bout = (const float*)d_in[6];
  const float* Wkey = (const float*)d_in[7];
  const float* bkey = (const float*)d_in[8];
  const float* alpha = (const float*)d_in[9];
  const float* gamma = (const float*)d_in[10];
  float* out = (float*)d_out;
  char* ws = (char*)d_ws;

  // zero the barrier region (ws is poisoned before every call)
  hipMemsetAsync(ws + 38888448, 0, 1024, stream);

  mann_mega<<<256, 512, 0, stream>>>(x_seq, Wih, Whh, bih, bhh, Wout, bout,
                                     Wkey, bkey, alpha, gamma, out, ws);
}

// Round 3
// 14584.233 us; speedup vs baseline: 2.6669x; 2.6669x over previous
//
#include <hip/hip_runtime.h>
#include <hip/hip_bf16.h>

// IN=128, H=512, N=2048, W=64, OUT=128, R=4, T=128, B=64
// ctrl_in=384, gate K=896, gate rows=2048, out+key rows=448
#define EPSF 1e-8f

typedef __attribute__((ext_vector_type(8))) __bf16 bf8;
typedef __attribute__((ext_vector_type(4))) float f4;

__device__ __forceinline__ short f2bf(float f) {
  union { __hip_bfloat16 b; short s; } u;
  u.b = __float2bfloat16(f);
  return u.s;
}
__device__ __forceinline__ float sigf(float x) { return 1.f / (1.f + __expf(-x)); }
__device__ __forceinline__ float red16(float v) {
  v += __shfl_xor(v, 1); v += __shfl_xor(v, 2);
  v += __shfl_xor(v, 4); v += __shfl_xor(v, 8);
  return v;
}

// Grid barrier, round k = 1,2,3,... Monotonic counters (no reset race).
// bar layout (unsigned words): arrival counters bar[g*8] (g<8, 32B apart),
// root bar[64], release flags bar[128 + g*16] (64B apart, <=32 pollers each).
// Polling uses RELAXED atomic RMW (fetch_add 0): executes at the coherence
// point (LLC) -> always fresh, and NO per-iteration cache invalidation
// (the R2 ACQUIRE-load spin emitted cache maintenance every poll -> ~74us).
// Fences once on entry (release) and once on exit (acquire).
__device__ __forceinline__ void gsync(unsigned* bar, unsigned k) {
  __syncthreads();
  if (threadIdx.x == 0) {
    __threadfence();  // release this block's writes to device scope
    const unsigned g = blockIdx.x >> 5;
    unsigned old = __hip_atomic_fetch_add(&bar[g * 8], 1u, __ATOMIC_RELAXED,
                                          __HIP_MEMORY_SCOPE_AGENT);
    if (old == k * 32u - 1u) {  // last block of this group
      unsigned rold = __hip_atomic_fetch_add(&bar[64], 1u, __ATOMIC_RELAXED,
                                             __HIP_MEMORY_SCOPE_AGENT);
      if (rold == k * 8u - 1u) {  // last group -> release all
        for (int j = 0; j < 8; ++j)
          __hip_atomic_fetch_add(&bar[128 + j * 16], 1u, __ATOMIC_RELAXED,
                                 __HIP_MEMORY_SCOPE_AGENT);
      }
    }
    while (__hip_atomic_fetch_add(&bar[128 + g * 16], 0u, __ATOMIC_RELAXED,
                                  __HIP_MEMORY_SCOPE_AGENT) < k)
      __builtin_amdgcn_s_sleep(2);
    __threadfence();  // acquire: invalidate stale cached data once
  }
  __syncthreads();
}

__global__ __launch_bounds__(512) void mann_mega(
    const float* __restrict__ x_seq, const float* __restrict__ Wih,
    const float* __restrict__ Whh, const float* __restrict__ bih,
    const float* __restrict__ bhh, const float* __restrict__ Wout,
    const float* __restrict__ boutp, const float* __restrict__ Wkey,
    const float* __restrict__ bkeyp, const float* __restrict__ alphap,
    const float* __restrict__ gammap, float* __restrict__ out, char* ws) {
  // workspace layout
  float* M = (float*)(ws);                    // 33554432
  float* rwA = (float*)(ws + 33554432);       // 2097152
  float* rwB = (float*)(ws + 35651584);       // 2097152
  float* usage = (float*)(ws + 37748736);     // 524288
  float* cst = (float*)(ws + 38273024);       // 131072
  short* hA = (short*)(ws + 38404096);        // 65536
  short* hB = (short*)(ws + 38469632);        // 65536
  float* rvp = (float*)(ws + 38535168);       // 262144  read_vec partials [b][ch][256]
  float* keys = (float*)(ws + 38797312);      // 81920
  float* sA = (float*)(ws + 38879232);        // 4096    sum partials [b][r][ch]
  float* sB = (float*)(ws + 38883328);        // 4096
  int* lu_idx = (int*)(ws + 38887424);        // 1024
  unsigned* bar = (unsigned*)(ws + 38888448); // 1024 (memset 0 by host each call)
  short* Wc = (short*)(ws + 38889472);        // 3670016
  short* Wkb = (short*)(ws + 42559488);       // 458752 -> end 43018240

  __shared__ union {
    struct { short Xs[64 * 72]; short Ws[32 * 72]; float gbuf[64 * 33]; } g;
    struct { float sv[512]; int si[512]; float wsum[32]; } r;
    struct { float rvacc[256]; } u;
  } sm;

  const int tid = threadIdx.x;
  const int lane = tid & 63;
  const int wv = tid >> 6;
  unsigned rnd = 0;

  // ---------------- prologue: weight cvt + state init ----------------
  {
    const unsigned gid = blockIdx.x * 512 + tid;
    const unsigned gs = 256 * 512;
    for (unsigned i = gid; i < 2048u * 896u; i += gs) {
      unsigned row = i / 896u, k = i - row * 896u;
      float v = (k < 384u) ? Wih[row * 384u + k] : Whh[row * 512u + (k - 384u)];
      Wc[i] = f2bf(v);
    }
    for (unsigned i = gid; i < 448u * 512u; i += gs) {
      unsigned row = i >> 9, k = i & 511u;
      float v = (row < 128u) ? Wout[row * 512u + k] : Wkey[(row - 128u) * 512u + k];
      Wkb[i] = f2bf(v);
    }
    for (unsigned i = gid; i < 8388608u; i += gs) M[i] = 1e-6f;
    for (unsigned i = gid; i < 524288u; i += gs) rwA[i] = 0.f;
    for (unsigned i = gid; i < 131072u; i += gs) usage[i] = 0.f;
    if (gid < 32768u) { cst[gid] = 0.f; hA[gid] = 0; }
    for (unsigned i = gid; i < 65536u; i += gs) rvp[i] = 0.f;
    if (gid < 1024u) sA[gid] = 0.25f;  // prev denom partials -> sum 1 (w_prev=0 via rwA=0)
  }
  gsync(bar, ++rnd);

  for (int t = 0; t < 128; ++t) {
    const short* hP = (t & 1) ? hB : hA;
    short* hN = (t & 1) ? hA : hB;
    const float* rwP = (t & 1) ? rwB : rwA;
    float* rwN = (t & 1) ? rwA : rwB;
    const float* sP = (t & 1) ? sB : sA;
    float* sN = (t & 1) ? sA : sB;

    // ---------------- P1: gates GEMM + LSTM cell (blocks 0..63) ----------------
    if (blockIdx.x < 64) {
      const int m = lane & 15, quad = lane >> 4;
      const int j0 = blockIdx.x * 8;
      f4 acc0 = {0.f, 0.f, 0.f, 0.f}, acc1 = {0.f, 0.f, 0.f, 0.f};
      for (int kc = 0; kc < 14; ++kc) {
        const int kbase = kc * 64;
        __syncthreads();
        if (kbase < 128) {
          for (int p = 0; p < 4; ++p) {
            int i = p * 512 + tid, row = i >> 5, kp = i & 31;
            float2 v = *(const float2*)&x_seq[((size_t)t * 64 + row) * 128 + kbase + kp * 2];
            short2 o; o.x = f2bf(v.x); o.y = f2bf(v.y);
            *(short2*)&sm.g.Xs[row * 72 + kp * 2] = o;
          }
        } else if (kbase < 384) {
          for (int p = 0; p < 4; ++p) {
            int i = p * 512 + tid, row = i >> 5, kp = i & 31;
            int col = kbase - 128 + kp * 2;
            float a0 = 0.f, a1 = 0.f;
#pragma unroll
            for (int cc = 0; cc < 4; ++cc) {
              float2 v = *(const float2*)&rvp[(row * 4 + cc) * 256 + col];
              a0 += v.x; a1 += v.y;
            }
            short2 o; o.x = f2bf(a0); o.y = f2bf(a1);
            *(short2*)&sm.g.Xs[row * 72 + kp * 2] = o;
          }
        } else {
          for (int p = 0; p < 4; ++p) {
            int i = p * 512 + tid, row = i >> 5, kp = i & 31;
            *(short2*)&sm.g.Xs[row * 72 + kp * 2] =
                *(const short2*)&hP[row * 512 + (kbase - 384) + kp * 2];
          }
        }
        for (int p = 0; p < 2; ++p) {
          int i = p * 512 + tid, row = i >> 5, kp = i & 31;
          int g = row >> 3, jj = row & 7;
          int grow = g * 512 + j0 + jj;
          *(short2*)&sm.g.Ws[row * 72 + kp * 2] =
              *(const short2*)&Wc[(size_t)grow * 896 + kbase + kp * 2];
        }
        __syncthreads();
        if (wv < 4) {
#pragma unroll
          for (int ki = 0; ki < 2; ++ki) {
            int ko = ki * 32 + quad * 8;
            bf8 a = *(const bf8*)&sm.g.Xs[(16 * wv + m) * 72 + ko];
            bf8 b0 = *(const bf8*)&sm.g.Ws[m * 72 + ko];
            bf8 b1 = *(const bf8*)&sm.g.Ws[(16 + m) * 72 + ko];
            acc0 = __builtin_amdgcn_mfma_f32_16x16x32_bf16(a, b0, acc0, 0, 0, 0);
            acc1 = __builtin_amdgcn_mfma_f32_16x16x32_bf16(a, b1, acc1, 0, 0, 0);
          }
        }
      }
      __syncthreads();
      if (wv < 4) {
#pragma unroll
        for (int reg = 0; reg < 4; ++reg) {
          int b = 16 * wv + quad * 4 + reg;
          sm.g.gbuf[b * 33 + m] = acc0[reg];
          sm.g.gbuf[b * 33 + 16 + m] = acc1[reg];
        }
      }
      __syncthreads();
      {
        int b = tid & 63, jj = tid >> 6, j = j0 + jj;
        float gi = sm.g.gbuf[b * 33 + jj] + bih[j] + bhh[j];
        float gf = sm.g.gbuf[b * 33 + 8 + jj] + bih[512 + j] + bhh[512 + j];
        float gg = sm.g.gbuf[b * 33 + 16 + jj] + bih[1024 + j] + bhh[1024 + j];
        float go = sm.g.gbuf[b * 33 + 24 + jj] + bih[1536 + j] + bhh[1536 + j];
        float co = cst[b * 512 + j];
        float cn = sigf(gf) * co + sigf(gi) * tanhf(gg);
        float hn = sigf(go) * tanhf(cn);
        cst[b * 512 + j] = cn;
        hN[b * 512 + j] = f2bf(hn);
      }
    }
    gsync(bar, ++rnd);

    // ---------------- P2: out + keys GEMM (blocks 0..13) ----------------
    if (blockIdx.x < 14) {
      const int m = lane & 15, quad = lane >> 4;
      const int row0 = blockIdx.x * 32;
      f4 a0 = {0.f, 0.f, 0.f, 0.f}, a1 = {0.f, 0.f, 0.f, 0.f};
      for (int kc = 0; kc < 8; ++kc) {
        int kbase = kc * 64;
        __syncthreads();
        for (int p = 0; p < 4; ++p) {
          int i = p * 512 + tid, row = i >> 5, kp = i & 31;
          *(short2*)&sm.g.Xs[row * 72 + kp * 2] =
              *(const short2*)&hN[row * 512 + kbase + kp * 2];
        }
        for (int p = 0; p < 2; ++p) {
          int i = p * 512 + tid, row = i >> 5, kp = i & 31;
          *(short2*)&sm.g.Ws[row * 72 + kp * 2] =
              *(const short2*)&Wkb[(size_t)(row0 + row) * 512 + kbase + kp * 2];
        }
        __syncthreads();
        if (wv < 4) {
#pragma unroll
          for (int ki = 0; ki < 2; ++ki) {
            int ko = ki * 32 + quad * 8;
            bf8 a = *(const bf8*)&sm.g.Xs[(16 * wv + m) * 72 + ko];
            bf8 b0 = *(const bf8*)&sm.g.Ws[m * 72 + ko];
            bf8 b1 = *(const bf8*)&sm.g.Ws[(16 + m) * 72 + ko];
            a0 = __builtin_amdgcn_mfma_f32_16x16x32_bf16(a, b0, a0, 0, 0, 0);
            a1 = __builtin_amdgcn_mfma_f32_16x16x32_bf16(a, b1, a1, 0, 0, 0);
          }
        }
      }
      if (wv < 4) {
#pragma unroll
        for (int f = 0; f < 2; ++f) {
          f4 av = f ? a1 : a0;
#pragma unroll
          for (int reg = 0; reg < 4; ++reg) {
            int b = 16 * wv + quad * 4 + reg;
            int grow = row0 + f * 16 + m;
            float val = av[reg];
            if (grow < 128)
              out[((size_t)t * 64 + b) * 128 + grow] = val + boutp[grow];
            else
              keys[b * 320 + (grow - 128)] = val + bkeyp[grow - 128];
          }
        }
      }
    }
    gsync(bar, ++rnd);

    // ---------------- P3: cosine sim + exp + partial sums + argmin ----------------
    {
      const int s = lane & 15, q = lane >> 4;
      const int b = blockIdx.x >> 2, ch = blockIdx.x & 3;
      const float4* M4 = (const float4*)M;
      const float4* K4 = (const float4*)keys;
      float4 kn[4];
#pragma unroll
      for (int r4 = 0; r4 < 4; ++r4) {
        float4 k4 = K4[b * 80 + r4 * 16 + s];
        float ss = k4.x * k4.x + k4.y * k4.y + k4.z * k4.z + k4.w * k4.w;
        ss = red16(ss);
        float iv = 1.f / (sqrtf(ss) + EPSF);
        kn[r4].x = k4.x * iv; kn[r4].y = k4.y * iv;
        kn[r4].z = k4.z * iv; kn[r4].w = k4.w * iv;
      }
      float es0 = 0.f, es1 = 0.f, es2 = 0.f, es3 = 0.f;
      for (int i = 0; i < 16; ++i) {
        int n = ch * 512 + wv * 64 + i * 4 + q;
        float4 m4 = M4[((size_t)b * 2048 + n) * 16 + s];
        float ssm = m4.x * m4.x + m4.y * m4.y + m4.z * m4.z + m4.w * m4.w;
        float d0 = m4.x * kn[0].x + m4.y * kn[0].y + m4.z * kn[0].z + m4.w * kn[0].w;
        float d1 = m4.x * kn[1].x + m4.y * kn[1].y + m4.z * kn[1].z + m4.w * kn[1].w;
        float d2 = m4.x * kn[2].x + m4.y * kn[2].y + m4.z * kn[2].z + m4.w * kn[2].w;
        float d3 = m4.x * kn[3].x + m4.y * kn[3].y + m4.z * kn[3].z + m4.w * kn[3].w;
        ssm = red16(ssm);
        d0 = red16(d0); d1 = red16(d1); d2 = red16(d2); d3 = red16(d3);
        float iv = 1.f / (sqrtf(ssm) + EPSF);
        if (s == 0) {
          float e0 = __expf(d0 * iv), e1 = __expf(d1 * iv);
          float e2 = __expf(d2 * iv), e3 = __expf(d3 * iv);
          rwN[(b * 4 + 0) * 2048 + n] = e0;
          rwN[(b * 4 + 1) * 2048 + n] = e1;
          rwN[(b * 4 + 2) * 2048 + n] = e2;
          rwN[(b * 4 + 3) * 2048 + n] = e3;
          es0 += e0; es1 += e1; es2 += e2; es3 += e3;
        }
      }
      es0 += __shfl_xor(es0, 16); es0 += __shfl_xor(es0, 32);
      es1 += __shfl_xor(es1, 16); es1 += __shfl_xor(es1, 32);
      es2 += __shfl_xor(es2, 16); es2 += __shfl_xor(es2, 32);
      es3 += __shfl_xor(es3, 16); es3 += __shfl_xor(es3, 32);
      if (lane == 0) {
        sm.r.wsum[wv * 4 + 0] = es0; sm.r.wsum[wv * 4 + 1] = es1;
        sm.r.wsum[wv * 4 + 2] = es2; sm.r.wsum[wv * 4 + 3] = es3;
      }
      __syncthreads();
      if (tid < 4) {
        float ssum = 0.f;
        for (int w8 = 0; w8 < 8; ++w8) ssum += sm.r.wsum[w8 * 4 + tid];
        sN[(b * 4 + tid) * 4 + ch] = ssum;
      }
      if (ch == 0) {
        float vm = INFINITY;
        int im = 0x7fffffff;
        for (int i2 = 0; i2 < 4; ++i2) {
          int n = i2 * 512 + tid;  // strictly increasing -> strict < keeps first min
          float v = usage[b * 2048 + n];
          if (v < vm) { vm = v; im = n; }
        }
        sm.r.sv[tid] = vm; sm.r.si[tid] = im;
        __syncthreads();
        for (int off = 256; off > 0; off >>= 1) {
          if (tid < off) {
            float v2 = sm.r.sv[tid + off]; int j2 = sm.r.si[tid + off];
            if (v2 < sm.r.sv[tid] || (v2 == sm.r.sv[tid] && j2 < sm.r.si[tid])) {
              sm.r.sv[tid] = v2; sm.r.si[tid] = j2;
            }
          }
          __syncthreads();
        }
        if (tid == 0) lu_idx[b] = sm.r.si[0];
      }
    }
    gsync(bar, ++rnd);

    // ---------------- P4: read_vec + memory write + usage update ----------------
    {
      const int s = lane & 15, q = lane >> 4;
      const int b = blockIdx.x >> 2, ch = blockIdx.x & 3;
      float4* M4 = (float4*)M;
      const float4* K4 = (const float4*)keys;
      const float sa = sigf(alphap[0]);
      const float gam = gammap[0];
      const int lu = lu_idx[b];
      const float4 wk = K4[b * 80 + 64 + s];
      float iN[4], iP[4];
#pragma unroll
      for (int r4 = 0; r4 < 4; ++r4) {
        float t0 = sN[(b * 4 + r4) * 4 + 0] + sN[(b * 4 + r4) * 4 + 1] +
                   sN[(b * 4 + r4) * 4 + 2] + sN[(b * 4 + r4) * 4 + 3];
        iN[r4] = 1.f / t0;
        float t1 = sP[(b * 4 + r4) * 4 + 0] + sP[(b * 4 + r4) * 4 + 1] +
                   sP[(b * 4 + r4) * 4 + 2] + sP[(b * 4 + r4) * 4 + 3];
        iP[r4] = 1.f / t1;
      }
      if (tid < 256) sm.u.rvacc[tid] = 0.f;
      __syncthreads();
      float4 rv0 = {0,0,0,0}, rv1 = {0,0,0,0}, rv2 = {0,0,0,0}, rv3 = {0,0,0,0};
      for (int i = 0; i < 16; ++i) {
        int n = ch * 512 + wv * 64 + i * 4 + q;
        size_t mi = ((size_t)b * 2048 + n) * 16 + s;
        float4 m4 = M4[mi];
        float e0 = rwN[(b * 4 + 0) * 2048 + n] * iN[0];
        float e1 = rwN[(b * 4 + 1) * 2048 + n] * iN[1];
        float e2 = rwN[(b * 4 + 2) * 2048 + n] * iN[2];
        float e3 = rwN[(b * 4 + 3) * 2048 + n] * iN[3];
        rv0.x += e0 * m4.x; rv0.y += e0 * m4.y; rv0.z += e0 * m4.z; rv0.w += e0 * m4.w;
        rv1.x += e1 * m4.x; rv1.y += e1 * m4.y; rv1.z += e1 * m4.z; rv1.w += e1 * m4.w;
        rv2.x += e2 * m4.x; rv2.y += e2 * m4.y; rv2.z += e2 * m4.z; rv2.w += e2 * m4.w;
        rv3.x += e3 * m4.x; rv3.y += e3 * m4.y; rv3.z += e3 * m4.z; rv3.w += e3 * m4.w;
        float wps = rwP[(b * 4 + 0) * 2048 + n] * iP[0] +
                    rwP[(b * 4 + 1) * 2048 + n] * iP[1] +
                    rwP[(b * 4 + 2) * 2048 + n] * iP[2] +
                    rwP[(b * 4 + 3) * 2048 + n] * iP[3];
        float onehot = (n == lu) ? 1.f : 0.f;
        float ww = sa * wps + (1.f - sa) * onehot;
        float keep = 1.f - onehot;
        float4 mn;
        mn.x = m4.x * keep + ww * wk.x;
        mn.y = m4.y * keep + ww * wk.y;
        mn.z = m4.z * keep + ww * wk.z;
        mn.w = m4.w * keep + ww * wk.w;
        M4[mi] = mn;
        if (s == 0)
          usage[b * 2048 + n] = gam * usage[b * 2048 + n] + (e0 + e1 + e2 + e3) + ww;
      }
#define REDQ(v) { v += __shfl_xor(v, 16); v += __shfl_xor(v, 32); }
      REDQ(rv0.x) REDQ(rv0.y) REDQ(rv0.z) REDQ(rv0.w)
      REDQ(rv1.x) REDQ(rv1.y) REDQ(rv1.z) REDQ(rv1.w)
      REDQ(rv2.x) REDQ(rv2.y) REDQ(rv2.z) REDQ(rv2.w)
      REDQ(rv3.x) REDQ(rv3.y) REDQ(rv3.z) REDQ(rv3.w)
#undef REDQ
      if (q == 0) {
        atomicAdd(&sm.u.rvacc[0 * 64 + s * 4 + 0], rv0.x);
        atomicAdd(&sm.u.rvacc[0 * 64 + s * 4 + 1], rv0.y);
        atomicAdd(&sm.u.rvacc[0 * 64 + s * 4 + 2], rv0.z);
        atomicAdd(&sm.u.rvacc[0 * 64 + s * 4 + 3], rv0.w);
        atomicAdd(&sm.u.rvacc[1 * 64 + s * 4 + 0], rv1.x);
        atomicAdd(&sm.u.rvacc[1 * 64 + s * 4 + 1], rv1.y);
        atomicAdd(&sm.u.rvacc[1 * 64 + s * 4 + 2], rv1.z);
        atomicAdd(&sm.u.rvacc[1 * 64 + s * 4 + 3], rv1.w);
        atomicAdd(&sm.u.rvacc[2 * 64 + s * 4 + 0], rv2.x);
        atomicAdd(&sm.u.rvacc[2 * 64 + s * 4 + 1], rv2.y);
        atomicAdd(&sm.u.rvacc[2 * 64 + s * 4 + 2], rv2.z);
        atomicAdd(&sm.u.rvacc[2 * 64 + s * 4 + 3], rv2.w);
        atomicAdd(&sm.u.rvacc[3 * 64 + s * 4 + 0], rv3.x);
        atomicAdd(&sm.u.rvacc[3 * 64 + s * 4 + 1], rv3.y);
        atomicAdd(&sm.u.rvacc[3 * 64 + s * 4 + 2], rv3.z);
        atomicAdd(&sm.u.rvacc[3 * 64 + s * 4 + 3], rv3.w);
      }
      __syncthreads();
      if (tid < 256) rvp[(b * 4 + ch) * 256 + tid] = sm.u.rvacc[tid];
    }
    gsync(bar, ++rnd);
  }
}

extern "C" void kernel_launch(void* const* d_in, const int* in_sizes, int n_in,
                              void* d_out, int out_size, void* d_ws, size_t ws_size,
                              hipStream_t stream) {
  const float* x_seq = (const float*)d_in[0];
  const float* Wih = (const float*)d_in[1];
  const float* Whh = (const float*)d_in[2];
  const float* bih = (const float*)d_in[3];
  const float* bhh = (const float*)d_in[4];
  const float* Wout = (const float*)d_in[5];
  const float* bout = (const float*)d_in[6];
  const float* Wkey = (const float*)d_in[7];
  const float* bkey = (const float*)d_in[8];
  const float* alpha = (const float*)d_in[9];
  const float* gamma = (const float*)d_in[10];
  float* out = (float*)d_out;
  char* ws = (char*)d_ws;

  // zero the barrier region (ws is poisoned before every call)
  hipMemsetAsync(ws + 38888448, 0, 1024, stream);

  mann_mega<<<256, 512, 0, stream>>>(x_seq, Wih, Whh, bih, bhh, Wout, bout,
                                     Wkey, bkey, alpha, gamma, out, ws);
}